// Round 1
// 206.638 us; speedup vs baseline: 1.0434x; 1.0434x over previous
//
#include <hip/hip_runtime.h>
#include <hip/hip_bf16.h>
#include <stdint.h>

#define K_DIM 4096
#define N_DIM 8192
#define NTILES (N_DIM / 128)          // 64 B-row tiles
#define FLAG_WORDS (NTILES * 4)       // 256 words: flags[ntile*4 + kchunk/32] bit (kchunk%32)

typedef __attribute__((ext_vector_type(8))) __bf16 bf16x8;
typedef __attribute__((ext_vector_type(8))) unsigned short u16x8;
typedef __attribute__((ext_vector_type(4))) float f32x4;

// ---------- quantization: nearest of {0,±1,±.5,±.333333,±.2,±.142857,±.090909,±.076923} ----------
// Tie-break matches the reference's first-min LUT scan:
//   boundary to 0 (index 0 first) -> strict >; between nonzero magnitudes -> >=
__device__ __forceinline__ float quantize_ws(float ws, float scale) {
    float a  = fabsf(ws);
    float v  = 0.0f;
    v = (a >  0.0384615f) ? 0.076923f : v;
    v = (a >= 0.0839160f) ? 0.090909f : v;
    v = (a >= 0.1168830f) ? 0.142857f : v;
    v = (a >= 0.1714285f) ? 0.2f      : v;
    v = (a >= 0.2666665f) ? 0.333333f : v;
    v = (a >= 0.4166665f) ? 0.5f      : v;
    v = (a >= 0.75f)      ? 1.0f      : v;
    v = copysignf(v, ws);
    return v * scale;
}

__device__ __forceinline__ unsigned short to_bf16(float f) {
    unsigned int u = __float_as_uint(f);
    u += 0x7FFFu + ((u >> 16) & 1u);   // RNE
    return (unsigned short)(u >> 16);
}

// ---------- pass 1: scan W -> sparsity flags (no Wq materialization) ----------
// |w/s| > 0.0384615  <=>  |w| > 0.0384615*|s|. Common case: whole wave's 256
// elements quantize to 0 -> pure HBM-read-bound (~12 VALU/iter). A wave spans
// 256 consecutive cols in one row -> one ntile, one 32-chunk flag word.
__global__ void scan_w_kernel(const float* __restrict__ W,
                              const float* __restrict__ scale_p,
                              unsigned int* __restrict__ flags, int n4) {
    const float th = 0.0384615f * fabsf(scale_p[0]);
    int idx    = blockIdx.x * blockDim.x + threadIdx.x;
    int stride = gridDim.x * blockDim.x;
    const float4* W4 = (const float4*)W;
    for (int i = idx; i < n4; i += stride) {
        float4 w = W4[i];
        float amax = fmaxf(fmaxf(fabsf(w.x), fabsf(w.y)), fmaxf(fabsf(w.z), fabsf(w.w)));
        bool big = amax > th;
        if (__ballot(big)) {                   // rare slow path
            int col    = (i << 2) & (K_DIM - 1);
            int row    = (i << 2) >> 12;       // /K_DIM
            int kchunk = col >> 5;
            int ntile  = row >> 7;
            unsigned int mask = big ? (1u << (kchunk & 31)) : 0u;
#pragma unroll
            for (int off = 32; off; off >>= 1) mask |= __shfl_down(mask, off, 64);
            if (((threadIdx.x & 63) == 0) && mask)
                atomicOr(&flags[ntile * 4 + (kchunk >> 5)], mask);
        }
    }
}

// ---------- pass 2: sparse-aware GEMM, C = x @ quant(W)^T, staging from fp32 ----------
// 128x128 tile, BK=32, 2x2 waves, 4x4 frags, 64 B LDS rows. Per-block early
// exit: all 4 flag words zero -> zero-fill own C tile (float4) and return.
// Nonzero chunks: stage A from fp32 x (bf16-convert) and B from fp32 W
// (quantize+convert) on the fly -- no Wq/Xb intermediates, no poison reads.
// Skipping a zero chunk is BIT-EXACT: every skipped term is acc += a*0.
__global__ __launch_bounds__(256) void gemm_bt_bf16(
        const float* __restrict__ X,            // [M][K] fp32
        const float* __restrict__ Wf,           // [N][K] fp32
        const float* __restrict__ scale_p,
        const unsigned int* __restrict__ flags,
        float* __restrict__ C, int M) {
    __shared__ unsigned short sA[128 * 32];     // row-major [m][k], 64 B rows
    __shared__ unsigned short sB[128 * 32];

    const int tid  = threadIdx.x;
    const int ntile = blockIdx.x & 63;          // N/128 = 64
    const int mtile = blockIdx.x >> 6;
    const int m0 = mtile * 128;
    const int n0 = ntile * 128;

    const unsigned int f0 = flags[ntile * 4 + 0];
    const unsigned int f1 = flags[ntile * 4 + 1];
    const unsigned int f2 = flags[ntile * 4 + 2];
    const unsigned int f3 = flags[ntile * 4 + 3];

    if ((f0 | f1 | f2 | f3) == 0u) {
        // whole B-row-tile quantizes to 0 -> this C tile is exactly 0.
        const float4 zz = {0.f, 0.f, 0.f, 0.f};
        float4* C4 = (float4*)(C + (size_t)m0 * N_DIM + n0);
#pragma unroll
        for (int g = tid; g < 128 * 32; g += 256) {   // 128 rows x 32 float4
            int r = g >> 5, c = g & 31;
            C4[(size_t)r * (N_DIM / 4) + c] = zz;
        }
        return;
    }

    const float s   = scale_p[0];
    const float inv = 1.0f / s;

    const int w    = tid >> 6;
    const int lane = tid & 63;
    const int quad = lane >> 4;
    const int l16  = lane & 15;
    const int wm   = w >> 1;                    // 2x2 wave grid
    const int wn   = w & 1;

    f32x4 acc[4][4];
    const f32x4 z = {0.f, 0.f, 0.f, 0.f};
#pragma unroll
    for (int i = 0; i < 4; ++i)
#pragma unroll
        for (int j = 0; j < 4; ++j) acc[i][j] = z;

    char* sAb = (char*)sA;
    char* sBb = (char*)sB;

    for (int k0 = 0; k0 < K_DIM; k0 += 32) {
        int ch = k0 >> 5;
        unsigned int word = (ch < 64) ? ((ch < 32) ? f0 : f1)
                                      : ((ch < 96) ? f2 : f3);
        if (!((word >> (ch & 31)) & 1u)) continue;   // block-uniform skip

        // stage 128x32: 512 groups of 8 elems; group g -> row g>>2, seg g&3.
        // Lanes 0..3 cover one row's 128 B contiguous fp32 -> coalesced.
#pragma unroll
        for (int p = 0; p < 2; ++p) {
            int g   = p * 256 + tid;
            int row = g >> 2;
            int seg = g & 3;
            const float* xa = X  + (size_t)(m0 + row) * K_DIM + k0 + seg * 8;
            const float* wb = Wf + (size_t)(n0 + row) * K_DIM + k0 + seg * 8;
            float4 a0 = *(const float4*)xa;
            float4 a1 = *(const float4*)(xa + 4);
            float4 b0 = *(const float4*)wb;
            float4 b1 = *(const float4*)(wb + 4);
            u16x8 qa, qb;
            qa[0] = to_bf16(a0.x); qa[1] = to_bf16(a0.y);
            qa[2] = to_bf16(a0.z); qa[3] = to_bf16(a0.w);
            qa[4] = to_bf16(a1.x); qa[5] = to_bf16(a1.y);
            qa[6] = to_bf16(a1.z); qa[7] = to_bf16(a1.w);
            qb[0] = to_bf16(quantize_ws(b0.x * inv, s));
            qb[1] = to_bf16(quantize_ws(b0.y * inv, s));
            qb[2] = to_bf16(quantize_ws(b0.z * inv, s));
            qb[3] = to_bf16(quantize_ws(b0.w * inv, s));
            qb[4] = to_bf16(quantize_ws(b1.x * inv, s));
            qb[5] = to_bf16(quantize_ws(b1.y * inv, s));
            qb[6] = to_bf16(quantize_ws(b1.z * inv, s));
            qb[7] = to_bf16(quantize_ws(b1.w * inv, s));
            *(u16x8*)(sAb + row * 64 + seg * 16) = qa;
            *(u16x8*)(sBb + row * 64 + seg * 16) = qb;
        }
        __syncthreads();

        bf16x8 af[4], bf[4];
#pragma unroll
        for (int i = 0; i < 4; ++i) {
            af[i] = *(const bf16x8*)(sAb + ((size_t)(wm * 64 + i * 16 + l16) * 32 + quad * 8) * 2);
            bf[i] = *(const bf16x8*)(sBb + ((size_t)(wn * 64 + i * 16 + l16) * 32 + quad * 8) * 2);
        }
#pragma unroll
        for (int mi = 0; mi < 4; ++mi)
#pragma unroll
            for (int ni = 0; ni < 4; ++ni)
                acc[mi][ni] = __builtin_amdgcn_mfma_f32_16x16x32_bf16(af[mi], bf[ni], acc[mi][ni], 0, 0, 0);
        __syncthreads();
    }

    // epilogue: D row = m (quad*4+reg), col = n (lane&15)  [verified mapping, m89/m91]
#pragma unroll
    for (int mi = 0; mi < 4; ++mi) {
#pragma unroll
        for (int ni = 0; ni < 4; ++ni) {
            int row = m0 + wm * 64 + mi * 16 + quad * 4;
            int col = n0 + wn * 64 + ni * 16 + l16;
#pragma unroll
            for (int r = 0; r < 4; ++r)
                C[(size_t)(row + r) * N_DIM + col] = acc[mi][ni][r];
        }
    }
}

// ---------- fallback (no usable workspace / odd M): fp32 tiled GEMM, quantize in staging ----------
__global__ __launch_bounds__(256) void gemm_fp32_fb(const float* __restrict__ A,
                                                    const float* __restrict__ B,
                                                    const float* __restrict__ scale_p,
                                                    float* __restrict__ C, int M) {
    __shared__ float sA[64][17];
    __shared__ float sB[64][17];
    const float s   = scale_p[0];
    const float inv = 1.0f / s;
    int tid = threadIdx.x;
    int tx = tid & 15, ty = tid >> 4;
    int n0 = (blockIdx.x & 127) * 64;          // N/64 = 128
    int m0 = (blockIdx.x >> 7) * 64;
    float acc[4][4] = {};
    for (int k0 = 0; k0 < K_DIM; k0 += 16) {
#pragma unroll
        for (int i = 0; i < 4; ++i) {
            int e = tid + i * 256;
            int r = e >> 4, c = e & 15;
            sA[r][c] = A[(size_t)(m0 + r) * K_DIM + k0 + c];
            sB[r][c] = quantize_ws(B[(size_t)(n0 + r) * K_DIM + k0 + c] * inv, s);
        }
        __syncthreads();
#pragma unroll
        for (int kk = 0; kk < 16; ++kk) {
            float a[4], b[4];
#pragma unroll
            for (int i = 0; i < 4; ++i) { a[i] = sA[ty * 4 + i][kk]; b[i] = sB[tx * 4 + i][kk]; }
#pragma unroll
            for (int i = 0; i < 4; ++i)
#pragma unroll
                for (int j = 0; j < 4; ++j) acc[i][j] += a[i] * b[j];
        }
        __syncthreads();
    }
#pragma unroll
    for (int i = 0; i < 4; ++i)
#pragma unroll
        for (int j = 0; j < 4; ++j)
            C[(size_t)(m0 + ty * 4 + i) * N_DIM + n0 + tx * 4 + j] = acc[i][j];
}

extern "C" void kernel_launch(void* const* d_in, const int* in_sizes, int n_in,
                              void* d_out, int out_size, void* d_ws, size_t ws_size,
                              hipStream_t stream) {
    const float* x     = (const float*)d_in[0];
    const float* W     = (const float*)d_in[1];
    const float* scale = (const float*)d_in[2];
    float* out = (float*)d_out;

    const int M = in_sizes[0] / K_DIM;                       // 1024
    const size_t fl_bytes = (size_t)FLAG_WORDS * sizeof(unsigned int);  // 1024 B

    if (ws_size >= fl_bytes && (M % 128) == 0) {
        unsigned int* flags = (unsigned int*)d_ws;
        int nW4 = (N_DIM * K_DIM) / 4;
        hipMemsetAsync(flags, 0, fl_bytes, stream);
        hipLaunchKernelGGL(scan_w_kernel, dim3(2048), dim3(256), 0, stream, W, scale, flags, nW4);
        hipLaunchKernelGGL(gemm_bt_bf16, dim3((M / 128) * (N_DIM / 128)), dim3(256), 0, stream,
                           x, W, scale, flags, out, M);
    } else {
        hipLaunchKernelGGL(gemm_fp32_fb, dim3((M / 64) * (N_DIM / 64)), dim3(256), 0, stream,
                           x, W, scale, out, M);
    }
}